// Round 1
// 657.739 us; speedup vs baseline: 1.1639x; 1.1639x over previous
//
#include <hip/hip_runtime.h>
#include <hip/hip_bf16.h>
#include <math.h>

// ---- static config (matches reference) ----
#define B_      8
#define DIMC    512
#define SEQ_    784
#define HEADS_  8
#define DH_     64
#define NTOK    (B_*SEQ_)      // 6272
#define QLD     1560           // q(512) | k(512) | v(512) | gates(24)
#define WIN_    196
#define CBS_    392
#define CST_    196
#define NC_     3
#define EPSF    1e-5f
#define FF_     2048
#define TQ_     28             // queries per block (28*28 = 784)
#define MT_     98             // m-tiles (6272/64)

typedef __hip_bfloat16 bf16_t;
typedef __attribute__((ext_vector_type(8))) short bf16x8;
typedef __attribute__((ext_vector_type(4))) float floatx4;
typedef __attribute__((ext_vector_type(4))) unsigned int uintx4;
typedef __attribute__((ext_vector_type(2))) unsigned int uintx2;

// ---------------- helpers ----------------
__device__ __forceinline__ float wsum(float x){
#pragma unroll
  for (int o = 32; o; o >>= 1) x += __shfl_xor(x, o, 64);
  return x;
}
__device__ __forceinline__ float geluf(float x){
  return 0.5f * x * (1.0f + erff(x * 0.70710678118654752f));
}
__device__ __forceinline__ float sigmoidf_(float x){
  return 1.0f / (1.0f + __expf(-x));
}

// ---------------- init: x[b,c,h,w] (f32) -> X[b,p,c] (f32) + pos ----------------
__global__ __launch_bounds__(256) void k_init(const float* __restrict__ xin,
                                              const float* __restrict__ pos,
                                              float* __restrict__ X){
  int idx = blockIdx.x * 256 + threadIdx.x;       // over NTOK*512 (exact)
  int c = idx & 511;
  int t = idx >> 9;          // b*784 + p
  int p = t % SEQ_;
  int b = t / SEQ_;
  float v = xin[((long)(b * DIMC + c)) * SEQ_ + p];
  X[idx] = v + pos[p];
}

// ---------------- final: X[b,p,c] -> out[b,c,h,w] f32 ----------------
__global__ __launch_bounds__(256) void k_final(const float* __restrict__ X,
                                               float* __restrict__ out){
  int idx = blockIdx.x * 256 + threadIdx.x;       // over B*DIMC*SEQ (exact)
  int p = idx % SEQ_;
  int t = idx / SEQ_;        // b*512 + c
  int c = t & 511;
  int b = t >> 9;
  out[idx] = X[((long)(b * SEQ_ + p)) * DIMC + c];
}

// ---------------- weight conversion: WQKVG [l][n 0..1559][k 0..511] bf16 (transposed) ----
__global__ __launch_bounds__(256) void k_wconv1(const float* __restrict__ Wq,
                                                const float* __restrict__ Wk,
                                                const float* __restrict__ Wv,
                                                const float* __restrict__ Wg,
                                                bf16_t* __restrict__ Wb){
  int idx = blockIdx.x * 256 + threadIdx.x;   // over 2*1560*512 (6240 blocks, exact)
  int k = idx & 511;
  int t = idx >> 9;
  int n = t % QLD;
  int l = t / QLD;
  float v;
  if (n < 1536){
    int which = n >> 9;
    int nn = n & 511;
    const float* W = (which == 0) ? Wq : ((which == 1) ? Wk : Wv);
    v = W[((long)(l * 512 + k)) * 512 + nn];
  } else {
    v = Wg[((long)(l * 512 + k)) * 24 + (n - 1536)];
  }
  Wb[idx] = __float2bfloat16(v);
}

// ---------------- WO transpose: Wb[l][n][k] = Wo[l][k][n] ----------------
__global__ __launch_bounds__(256) void k_wconv2(const float* __restrict__ Wo,
                                                bf16_t* __restrict__ Wb){
  int idx = blockIdx.x * 256 + threadIdx.x;   // over 2*512*512 (2048 blocks)
  int k = idx & 511;
  int t = idx >> 9;
  int n = t & 511;
  int l = t >> 9;
  Wb[idx] = __float2bfloat16(Wo[((long)(l * 512 + k)) * 512 + n]);
}

// ---------------- plain f32 -> bf16 cast ----------------
__global__ __launch_bounds__(256) void k_cast(const float* __restrict__ src,
                                              bf16_t* __restrict__ dst){
  int idx = blockIdx.x * 256 + threadIdx.x;
  dst[idx] = __float2bfloat16(src[idx]);
}

// ---------------- 16B-granular zero fill ----------------
__global__ __launch_bounds__(256) void k_zero(uintx4* __restrict__ p){
  p[blockIdx.x * 256 + threadIdx.x] = (uintx4){0u, 0u, 0u, 0u};
}

// ---------------- RMSNorm: f32 in -> bf16 out ----------------
__global__ __launch_bounds__(256) void k_rms(const float* __restrict__ X,
                                             const float* __restrict__ g,
                                             bf16_t* __restrict__ XR){
  int tok = blockIdx.x;
  int tid = threadIdx.x;
  const float* xr = X + (long)tok * DIMC;
  float v0 = xr[tid], v1 = xr[tid + 256];
  float ss = v0 * v0 + v1 * v1;
  ss = wsum(ss);
  __shared__ float red[4];
  if ((tid & 63) == 0) red[tid >> 6] = ss;
  __syncthreads();
  float tot = red[0] + red[1] + red[2] + red[3];
  float r = rsqrtf(tot * (1.0f / DIMC) + EPSF);
  XR[(long)tok * DIMC + tid]       = __float2bfloat16(v0 * r * g[tid]);
  XR[(long)tok * DIMC + tid + 256] = __float2bfloat16(v1 * r * g[tid + 256]);
}

// ---------------- LayerNorm: f32 in -> bf16 out ----------------
__global__ __launch_bounds__(256) void k_ln(const float* __restrict__ X,
                                            const float* __restrict__ g,
                                            const float* __restrict__ bb,
                                            bf16_t* __restrict__ XN){
  int tok = blockIdx.x;
  int tid = threadIdx.x;
  const float* xr = X + (long)tok * DIMC;
  float v0 = xr[tid], v1 = xr[tid + 256];
  float s = v0 + v1;
  float q = v0 * v0 + v1 * v1;
  s = wsum(s); q = wsum(q);
  __shared__ float r1[4], r2[4];
  if ((tid & 63) == 0){ r1[tid >> 6] = s; r2[tid >> 6] = q; }
  __syncthreads();
  float ts = r1[0] + r1[1] + r1[2] + r1[3];
  float tq = r2[0] + r2[1] + r2[2] + r2[3];
  float mean = ts * (1.0f / DIMC);
  float var  = tq * (1.0f / DIMC) - mean * mean;
  float rinv = rsqrtf(var + EPSF);
  XN[(long)tok * DIMC + tid]       = __float2bfloat16((v0 - mean) * rinv * g[tid]       + bb[tid]);
  XN[(long)tok * DIMC + tid + 256] = __float2bfloat16((v1 - mean) * rinv * g[tid + 256] + bb[tid + 256]);
}

// ---------------- bf16 MFMA GEMM: dbuf LDS + register prefetch, 1 barrier/chunk -----
// VTo != nullptr (QKVG GEMM only): also write V columns (ncol in [1024,1536))
// transposed to VTo[b*512 + d][tok] (bf16, row width 800; cols 784..799 pre-zeroed).
template<int OUTBF, int ACT>
__global__ __launch_bounds__(256) void k_mgemm(const bf16_t* __restrict__ A,
                                               const bf16_t* __restrict__ Bm,
                                               float* Cf,
                                               bf16_t* Cb,
                                               const float* __restrict__ bias,
                                               const float* res,
                                               int M, int N, int K, int ldc, int ccol,
                                               bf16_t* VTo){
  int id = blockIdx.x;
  int xcd = id & 7;
  int j = id >> 3;
  int nt = j / 13;
  int mt = xcd * 13 + (j - nt * 13);
  if (mt >= MT_) return;
  int bm = mt * 64, bn = nt * 64;

  __shared__ bf16_t As[2][64][40];   // 32 k + 8 pad, double-buffered
  __shared__ bf16_t Bs[2][64][40];
  int tid = threadIdx.x;
  int w = tid >> 6, lane = tid & 63;
  int wm = (w & 1) * 32, wn = (w >> 1) * 32;
  int quad = lane >> 4, l16 = lane & 15;

  int lrow = tid >> 2, lkc = (tid & 3) * 8;
  bool bok = (bn + lrow) < N;
  const bf16_t* ap = A + (long)(bm + lrow) * K + lkc;
  const bf16_t* bp = Bm + (long)(bok ? bn + lrow : 0) * K + lkc;

  floatx4 acc[2][2];
#pragma unroll
  for (int i = 0; i < 2; i++)
#pragma unroll
    for (int jj = 0; jj < 2; jj++) acc[i][jj] = (floatx4)(0.0f);

  uintx4 areg = *(const uintx4*)ap;
  uintx4 breg = *(const uintx4*)bp;
  if (!bok) breg = (uintx4){0u,0u,0u,0u};

  int nch = K >> 5;
  for (int ch = 0; ch < nch; ch++){
    int buf = ch & 1;
    *(uintx4*)&As[buf][lrow][lkc] = areg;
    *(uintx4*)&Bs[buf][lrow][lkc] = breg;
    if (ch + 1 < nch){
      areg = *(const uintx4*)(ap + (ch + 1) * 32);
      breg = *(const uintx4*)(bp + (ch + 1) * 32);
      if (!bok) breg = (uintx4){0u,0u,0u,0u};
    }
    __syncthreads();
    bf16x8 a0 = *(bf16x8*)&As[buf][wm + l16][quad * 8];
    bf16x8 a1 = *(bf16x8*)&As[buf][wm + 16 + l16][quad * 8];
    bf16x8 b0 = *(bf16x8*)&Bs[buf][wn + l16][quad * 8];
    bf16x8 b1 = *(bf16x8*)&Bs[buf][wn + 16 + l16][quad * 8];
    acc[0][0] = __builtin_amdgcn_mfma_f32_16x16x32_bf16(a0, b0, acc[0][0], 0, 0, 0);
    acc[0][1] = __builtin_amdgcn_mfma_f32_16x16x32_bf16(a0, b1, acc[0][1], 0, 0, 0);
    acc[1][0] = __builtin_amdgcn_mfma_f32_16x16x32_bf16(a1, b0, acc[1][0], 0, 0, 0);
    acc[1][1] = __builtin_amdgcn_mfma_f32_16x16x32_bf16(a1, b1, acc[1][1], 0, 0, 0);
    // no trailing barrier: next iter writes the other buffer; re-write of this
    // buffer happens only after the next barrier, which is after all reads here.
  }
#pragma unroll
  for (int tm = 0; tm < 2; tm++){
#pragma unroll
    for (int tn = 0; tn < 2; tn++){
      int ncol = bn + wn + tn * 16 + l16;
      if (ncol >= N) continue;
#pragma unroll
      for (int reg = 0; reg < 4; reg++){
        long mrow = bm + wm + tm * 16 + quad * 4 + reg;
        float v = acc[tm][tn][reg];
        if (bias) v += bias[ncol];
        if (ACT == 1) v = geluf(v);
        long off = mrow * (long)ldc + ccol + ncol;
        if (res) v += res[off];
        if (OUTBF){
          Cb[off] = __float2bfloat16(v);
          if (VTo && ncol >= 1024 && ncol < 1536){
            int bb2 = (int)mrow / SEQ_;
            int tok = (int)mrow - bb2 * SEQ_;
            VTo[((long)(bb2 * 512 + (ncol - 1024))) * 800 + tok] = __float2bfloat16(v);
          }
        }
        else       Cf[off] = v;
      }
    }
  }
}

// ---------------- compressed-block mean pooling, vectorized + coalesced -------------
__global__ __launch_bounds__(512) void k_cpool(const bf16_t* __restrict__ qkvg,
                                               float* __restrict__ ck,
                                               float* __restrict__ cv){
  int bj = blockIdx.x;
  int j = bj % NC_;
  int b = bj / NC_;
  int tid = threadIdx.x;
  int seg = tid & 127;
  int rg  = tid >> 7;
  __shared__ float part[4][1024];
  const bf16_t* base = qkvg + ((long)b * SEQ_ + (long)j * CST_) * QLD + 512;
  float acc[8] = {0.f,0.f,0.f,0.f,0.f,0.f,0.f,0.f};
  for (int r = rg; r < CBS_; r += 4){
    uintx4 v = *(const uintx4*)(base + (long)r * QLD + seg * 8);
    bf16_t tmp[8]; *(uintx4*)tmp = v;
#pragma unroll
    for (int q = 0; q < 8; q++) acc[q] += __bfloat162float(tmp[q]);
  }
#pragma unroll
  for (int q = 0; q < 8; q++) part[rg][seg * 8 + q] = acc[q];
  __syncthreads();
  for (int c = tid; c < 1024; c += 512){
    float s = (part[0][c] + part[1][c]) + (part[2][c] + part[3][c]);
    s *= (1.0f / CBS_);
    if (c < 512) ck[bj * DIMC + c] = s;
    else         cv[bj * DIMC + (c - 512)] = s;
  }
}

// ---------------- fused NSA attention v6 -------------------------------------------
// v6 changes vs v5 (latency-bound per rocprof: MfmaUtil 3.3%, VALU 36.7%, 60% idle):
//  * Phase C computes S^T = mfma(K,Q): each lane holds 4 consecutive KEYS of one
//    q-row -> packed ds_write_b64 score stores (was 8 scalar b16) AND in-register
//    window/selection row-sum accumulation (kills the serial scalar-LDS row-sum
//    phase; 2x shfl_xor + 1KB LDS cross-wave combine instead).
//  * Phase D B-fragments load directly from pre-transposed global VT[b*512+d][800]
//    (written by the QKVG GEMM epilogue; cols 784..799 zeroed once) -> no V LDS
//    staging, no Phase-D barriers, 2-deep global prefetch, 25 flat MFMA steps.
//  * build-W vectorized b128 (was per-element scalar LDS RMW).
// LDS 77040 B -> still 2 blocks/CU. outc_s sits right after sbuf so the benign
// sbuf row-28..31 A-fragment over-reads (discarded rows) stay inside the block.
__global__ __launch_bounds__(256) void k_attn(const bf16_t* __restrict__ qkvg,
                                              const float* __restrict__ ck,
                                              const float* __restrict__ cv,
                                              const bf16_t* __restrict__ vtg,
                                              bf16_t* __restrict__ oattn){
  int tid = threadIdx.x;
  int w = tid >> 6, lane = tid & 63;
  int quad = lane >> 4, l16 = lane & 15;
  int id = blockIdx.x;
  int xcd = id & 7;
  int j = id >> 3;               // 0..223
  int bh = xcd * 8 + (j / 28);   // all 28 tiles of a bh on one XCD
  int i0 = (j % 28) * TQ_;
  int h = bh & 7, b = bh >> 3;
  const float scale = 0.125f;

  __shared__ __align__(16) char smem[77040];
  bf16_t (*Qs)[72]    = (bf16_t(*)[72])(smem);             // 4608 B (rows 28-31 zero)
  bf16_t (*Ks0)[72]   = (bf16_t(*)[72])(smem + 4608);      // 9216 B (dbuf 0, 64 keys)
  bf16_t (*Ks1)[72]   = (bf16_t(*)[72])(smem + 13824);     // 9216 B (dbuf 1)
  bf16_t (*sbuf)[808] = (bf16_t(*)[808])(smem + 23040);    // 45248 B
  float  (*outc_s)[64]= (float(*)[64])(smem + 68288);      // 7168 B (absorbs overreads)
  int*   sel_s = (int*)(smem + 75456);                     // 112 B
  float* cw_s  = (float*)(smem + 75568);                   // 112 B
  float* cs_s  = (float*)(smem + 75680);                   // 112 B
  float* g1_s  = (float*)(smem + 75792);                   // 112 B
  float* g2_s  = (float*)(smem + 75904);                   // 112 B
  float (*red_s)[4][16] = (float(*)[4][16])(smem + 76016); // 1024 B

  const long rowBase = (long)b * SEQ_ * QLD + h * 64;     // + token*QLD + {0,512,1024}

  // ---- Phase A: stage Q tile (28 rows) + zero rows 28-31 ----
  if (tid < 224){
    int q = tid >> 3, seg = tid & 7;
    uintx4 qv = *(const uintx4*)(qkvg + rowBase + (long)(i0 + q) * QLD + seg * 8);
    *(uintx4*)&Qs[q][seg * 8] = qv;
  } else {
    int u = tid - 224;
    int r = 28 + (u >> 3), seg = u & 7;
    *(uintx4*)&Qs[r][seg * 8] = (uintx4){0u, 0u, 0u, 0u};
  }
  __syncthreads();

  // ---- prefetch K chunk 0 (latency hidden under Phase B) ----
  int r0i = tid >> 3, s0i = tid & 7;
  int r1i = 32 + r0i;
  uintx4 kreg0 = *(const uintx4*)(qkvg + rowBase + (long)r0i * QLD + 512 + s0i * 8);
  uintx4 kreg1 = *(const uintx4*)(qkvg + rowBase + (long)r1i * QLD + 512 + s0i * 8);

  // ---- Phase B: compressed branch + gates + top-1 selection ----
  {
    const float* CKp = ck + (long)b * NC_ * DIMC + h * 64 + lane;
    const float* CVp = cv + (long)b * NC_ * DIMC + h * 64 + lane;
    float k0 = CKp[0], k1 = CKp[512], k2 = CKp[1024];
    float v0 = CVp[0], v1 = CVp[512], v2 = CVp[1024];
#pragma unroll
    for (int qp = 0; qp < 7; qp++){
      int qg = w * 7 + qp;
      float qd = __bfloat162float(Qs[qg][lane]);
      float s0 = wsum(qd * k0) * scale;
      float s1 = wsum(qd * k1) * scale;
      float s2 = wsum(qd * k2) * scale;
      float m3 = fmaxf(s0, fmaxf(s1, s2));
      float e0 = __expf(s0 - m3), e1 = __expf(s1 - m3), e2 = __expf(s2 - m3);
      float inv = 1.0f / (e0 + e1 + e2);
      const bf16_t* grow = qkvg + (long)(b * SEQ_ + i0 + qg) * QLD + 1536 + h * 3;
      float g0 = sigmoidf_(__bfloat162float(grow[0]));
      float g1v = sigmoidf_(__bfloat162float(grow[1]));
      float g2v = sigmoidf_(__bfloat162float(grow[2]));
      outc_s[qg][lane] = g0 * (e0 * v0 + e1 * v1 + e2 * v2) * inv;
      int selv = (s2 > s0) ? 1 : 0;   // imp1>imp0 <=> p2>p0 <=> s2>s0
      if (lane == 0){ sel_s[qg] = selv; g1_s[qg] = g1v; g2_s[qg] = g2v; }
    }
  }

  // hoist Q B-fragments (chunk-invariant)
  bf16x8 a00 = *(bf16x8*)&Qs[l16][quad * 8];
  bf16x8 a01 = *(bf16x8*)&Qs[l16][32 + quad * 8];
  bf16x8 a10 = *(bf16x8*)&Qs[16 + l16][quad * 8];
  bf16x8 a11 = *(bf16x8*)&Qs[16 + l16][32 + quad * 8];

  __syncthreads();   // sel_s/g1_s/g2_s/outc_s visible to all waves

  // ---- Phase C: S^T = K.Q^T via MFMA (13 chunks of 64 keys, dbuf + reg prefetch) --
  // Lane (quad,l16) of wave w holds keys ch*64 + w*16 + quad*4 + {0..3} for
  // q = l16 (d0) and q = 16+l16 (d1): packed b64 score stores + in-reg row sums.
  int sel0i = sel_s[l16];
  int sel1i = (l16 < 12) ? sel_s[16 + l16] : 0;
  bool sv0 = (sel0i != 0), sv1 = (sel1i != 0);
  int iq0 = i0 + l16, iq1 = i0 + 16 + l16;
  float sw0 = 0.f, ss0 = 0.f, sw1 = 0.f, ss1 = 0.f;

  for (int ch = 0; ch < 13; ch++){
    bf16_t (*Kb)[72] = (ch & 1) ? Ks1 : Ks0;
    *(uintx4*)&Kb[r0i][s0i * 8] = kreg0;
    *(uintx4*)&Kb[r1i][s0i * 8] = kreg1;
    if (ch + 1 < 13){
      int c0n = (ch + 1) * 64;
      int t0 = c0n + r0i; if (t0 > 783) t0 = 783;
      int t1 = c0n + r1i; if (t1 > 783) t1 = 783;
      kreg0 = *(const uintx4*)(qkvg + rowBase + (long)t0 * QLD + 512 + s0i * 8);
      kreg1 = *(const uintx4*)(qkvg + rowBase + (long)t1 * QLD + 512 + s0i * 8);
    }
    __syncthreads();
    bf16x8 k0 = *(bf16x8*)&Kb[w * 16 + l16][quad * 8];
    bf16x8 k1 = *(bf16x8*)&Kb[w * 16 + l16][32 + quad * 8];
    floatx4 d0 = (floatx4)(0.0f), d1 = (floatx4)(0.0f);
    d0 = __builtin_amdgcn_mfma_f32_16x16x32_bf16(k0, a00, d0, 0, 0, 0);
    d0 = __builtin_amdgcn_mfma_f32_16x16x32_bf16(k1, a01, d0, 0, 0, 0);
    d1 = __builtin_amdgcn_mfma_f32_16x16x32_bf16(k0, a10, d1, 0, 0, 0);
    d1 = __builtin_amdgcn_mfma_f32_16x16x32_bf16(k1, a11, d1, 0, 0, 0);
    int kb = ch * 64 + w * 16 + quad * 4;
    union { bf16_t hh[4]; uintx2 v; } p0, p1;
#pragma unroll
    for (int r = 0; r < 4; r++){
      int key = kb + r;
      float ex0 = __expf(d0[r] * scale);
      float ex1 = __expf(d1[r] * scale);
      bool valid = key < 784;
      if (valid && key >= iq0 - 195 && key <= iq0 + 195) sw0 += ex0;
      if (valid && ((key >= 392) == sv0))                ss0 += ex0;
      if (valid && key >= iq1 - 195 && key <= iq1 + 195) sw1 += ex1;
      if (valid && ((key >= 392) == sv1))                ss1 += ex1;
      p0.hh[r] = __float2bfloat16(ex0);
      p1.hh[r] = __float2bfloat16(ex1);
    }
    if (kb < 784){
      *(uintx2*)&sbuf[l16][kb] = p0.v;
      if (l16 < 12) *(uintx2*)&sbuf[16 + l16][kb] = p1.v;
    }
    // next iter writes the other buffer; rewrite of this one is after next barrier
  }

  // ---- combine row sums: quads via shfl, waves via 1KB LDS ----
  sw0 += __shfl_xor(sw0, 16, 64); sw0 += __shfl_xor(sw0, 32, 64);
  ss0 += __shfl_xor(ss0, 16, 64); ss0 += __shfl_xor(ss0, 32, 64);
  sw1 += __shfl_xor(sw1, 16, 64); sw1 += __shfl_xor(sw1, 32, 64);
  ss1 += __shfl_xor(ss1, 16, 64); ss1 += __shfl_xor(ss1, 32, 64);
  if (quad == 0){
    red_s[w][0][l16] = sw0; red_s[w][1][l16] = ss0;
    red_s[w][2][l16] = sw1; red_s[w][3][l16] = ss1;
  }
  __syncthreads();
  if (tid < 28){
    int q = tid, t = q >> 4, l = q & 15;
    float sw = 0.f, ss = 0.f;
#pragma unroll
    for (int wv = 0; wv < 4; wv++){ sw += red_s[wv][2 * t][l]; ss += red_s[wv][2 * t + 1][l]; }
    cw_s[q] = g2_s[q] / sw;
    cs_s[q] = g1_s[q] / ss;
  }
  __syncthreads();

  // ---- prefetch first V fragment (hidden under build-W) ----
  const bf16_t* vrow = vtg + ((long)(b * 512 + h * 64 + w * 16 + l16)) * 800 + quad * 8;
  bf16x8 bv = *(const bf16x8*)vrow;

  // ---- build combined weight matrix W in place (b128; zero cols 784..799) ----
  for (int t = tid; t < 2800; t += 256){
    int q = t / 100;
    int c0 = (t - q * 100) * 8;
    uintx4 ov;
    if (c0 >= 784){
      ov = (uintx4){0u, 0u, 0u, 0u};
    } else {
      union { bf16_t hh[8]; uintx4 v; } in, out;
      in.v = *(uintx4*)&sbuf[q][c0];
      int iq = i0 + q;
      float cwv = cw_s[q], csv = cs_s[q];
      float cse = ((c0 >= 392) == (sel_s[q] != 0)) ? csv : 0.0f;
#pragma unroll
      for (int jj = 0; jj < 8; jj++){
        int c = c0 + jj;
        float coef = cse;
        if (c >= iq - 195 && c <= iq + 195) coef += cwv;
        out.hh[jj] = __float2bfloat16(__bfloat162float(in.hh[jj]) * coef);
      }
      ov = out.v;
    }
    *(uintx4*)&sbuf[q][c0] = ov;
  }
  __syncthreads();

  // ---- Phase D: out = W . V via MFMA, V fragments straight from global VT --------
  floatx4 o0 = (floatx4)(0.0f), o1 = (floatx4)(0.0f);
#pragma unroll 5
  for (int st = 0; st < 25; st++){
    bf16x8 bcur = bv;
    if (st + 1 < 25) bv = *(const bf16x8*)(vrow + (st + 1) * 32);
    int kc = st * 32 + quad * 8;
    bf16x8 av0 = *(bf16x8*)&sbuf[l16][kc];
    bf16x8 av1 = *(bf16x8*)&sbuf[16 + l16][kc];
    o0 = __builtin_amdgcn_mfma_f32_16x16x32_bf16(av0, bcur, o0, 0, 0, 0);
    o1 = __builtin_amdgcn_mfma_f32_16x16x32_bf16(av1, bcur, o1, 0, 0, 0);
  }

  // ---- epilogue: add compressed branch, write bf16 ----
  int d = w * 16 + l16;
#pragma unroll
  for (int reg = 0; reg < 4; reg++){
    int q = quad * 4 + reg;
    float o = o0[reg] + outc_s[q][d];
    oattn[((long)(b * SEQ_ + i0 + q)) * DIMC + h * 64 + d] = __float2bfloat16(o);
    int q2 = q + 16;
    if (q2 < 28){
      float o2 = o1[reg] + outc_s[q2][d];
      oattn[((long)(b * SEQ_ + i0 + q2)) * DIMC + h * 64 + d] = __float2bfloat16(o2);
    }
  }
}

// ---------------- host launcher ----------------
extern "C" void kernel_launch(void* const* d_in, const int* in_sizes, int n_in,
                              void* d_out, int out_size, void* d_ws, size_t ws_size,
                              hipStream_t stream){
  const float* xin  = (const float*)d_in[0];
  const float* pos  = (const float*)d_in[1];
  const float* angm = (const float*)d_in[2];
  const float* Wq   = (const float*)d_in[3];
  const float* Wk   = (const float*)d_in[4];
  const float* Wv   = (const float*)d_in[5];
  const float* Wo   = (const float*)d_in[6];
  const float* Wg   = (const float*)d_in[7];
  const float* fng  = (const float*)d_in[8];
  const float* fnb  = (const float*)d_in[9];
  const float* fw1  = (const float*)d_in[10];
  const float* fb1  = (const float*)d_in[11];
  const float* fw2  = (const float*)d_in[12];
  const float* fb2  = (const float*)d_in[13];

  // workspace layout: ~70.7 MB total (BUFb/H1b share one region — disjoint live ranges)
  char* cw = (char*)d_ws;
  float* X = (float*)cw;             cw += (long)NTOK * 512 * 4;     // 12.85 MB
  bf16_t* XRb = (bf16_t*)cw;         cw += (long)NTOK * 512 * 2;     //  6.42 MB
  bf16_t* OAb = (bf16_t*)cw;         cw += (long)NTOK * 512 * 2;     //  6.42 MB
  bf16_t* SH  = (bf16_t*)cw;         cw += (long)NTOK * FF_ * 2;     // 25.69 MB (BUFb/H1b)
  float* CK = (float*)cw;            cw += (long)B_ * NC_ * DIMC * 4;
  float* CV = (float*)cw;            cw += (long)B_ * NC_ * DIMC * 4;
  bf16_t* Wqkvgb = (bf16_t*)cw;      cw += (long)2 * QLD * 512 * 2;  //  3.19 MB
  bf16_t* WOb    = (bf16_t*)cw;      cw += (long)2 * 512 * 512 * 2;  //  1.05 MB
  bf16_t* FW1b   = (bf16_t*)cw;      cw += (long)2 * FF_ * 512 * 2;  //  4.19 MB
  bf16_t* FW2b   = (bf16_t*)cw;      cw += (long)2 * 512 * FF_ * 2;  //  4.19 MB
  bf16_t* VTb    = (bf16_t*)cw;      cw += (long)B_ * 512 * 800 * 2; //  6.55 MB
  bf16_t* BUFb = SH;   // [NTOK, QLD]  (QKVG output; dies after k_attn)
  bf16_t* H1b  = SH;   // [NTOK, FF_]  (FF1 output; born after k_ln)

  // per-call weight conversion (deterministic, same work every call)
  k_wconv1<<<(2 * QLD * 512) / 256, 256, 0, stream>>>(Wq, Wk, Wv, Wg, Wqkvgb);
  k_wconv2<<<(2 * 512 * 512) / 256, 256, 0, stream>>>(Wo, WOb);
  k_cast<<<(2 * FF_ * 512) / 256, 256, 0, stream>>>(fw1, FW1b);
  k_cast<<<(2 * 512 * FF_) / 256, 256, 0, stream>>>(fw2, FW2b);

  // zero VT once: tokens 784..799 stay zero; cols 0..783 rewritten each layer
  k_zero<<<1600, 256, 0, stream>>>((uintx4*)VTb);   // 6,553,600 B

  k_init<<<12544, 256, 0, stream>>>(xin, pos, X);

  for (int l = 0; l < 2; l++){
    k_rms<<<NTOK, 256, 0, stream>>>(X, angm + (long)l * DIMC, XRb);

    // fused QKV+G GEMM: [6272,512] x [1560,512]^T -> BUFb [6272,1560] bf16 (+ VT)
    k_mgemm<1, 0><<<25 * 104, 256, 0, stream>>>(
        XRb, Wqkvgb + (long)l * QLD * 512, nullptr, BUFb, nullptr, nullptr,
        NTOK, QLD, 512, QLD, 0, VTb);

    k_cpool<<<B_ * NC_, 512, 0, stream>>>(BUFb, CK, CV);

    k_attn<<<8 * 8 * 28, 256, 0, stream>>>(BUFb, CK, CV, VTb, OAb);

    // Wo GEMM: f32 out + residual into X
    k_mgemm<0, 0><<<8 * 104, 256, 0, stream>>>(
        OAb, WOb + (long)l * 512 * 512, X, nullptr, nullptr, X,
        NTOK, 512, 512, 512, 0, nullptr);

    k_ln<<<NTOK, 256, 0, stream>>>(X, fng + (long)l * DIMC, fnb + (long)l * DIMC, XRb);

    // FF1 + GELU, bf16 out into H1b
    k_mgemm<1, 1><<<32 * 104, 256, 0, stream>>>(
        XRb, FW1b + (long)l * FF_ * 512, nullptr, H1b, fb1 + (long)l * FF_, nullptr,
        NTOK, FF_, 512, FF_, 0, nullptr);
    // FF2, f32 out + residual into X
    k_mgemm<0, 0><<<8 * 104, 256, 0, stream>>>(
        H1b, FW2b + (long)l * 512 * FF_, X, nullptr, fb2 + (long)l * DIMC, X,
        NTOK, 512, FF_, 512, 0, nullptr);
  }

  k_final<<<12544, 256, 0, stream>>>(X, (float*)d_out);
}